// Round 8
// baseline (464.422 us; speedup 1.0000x reference)
//
#include <hip/hip_runtime.h>
#include <math.h>

// Problem constants
#define B_ 16
#define C_ 64
#define H_ 128
#define W_ 128
#define HW_ (H_*W_)
#define OUT_ELEMS 16777216   // B*C*H*W

// Workspace byte offsets
#define CHM_B    0                      // 512 f32
#define PWA_B    2048                   // 16384 u16
#define AH_B     34816                  // 258048 u16
#define FEA_B(s) (550912u + (size_t)(s)*33554432u)  // 4 x 16777216 u16

// A-image u16 offsets within AH
#define A_S0   0
#define A_S(s) (36864 + ((s)-1)*73728)  // s = 1..3

typedef __attribute__((ext_vector_type(4))) short  v4s;
typedef __attribute__((ext_vector_type(8))) short  v8s;
typedef __attribute__((ext_vector_type(4))) float  v4f;

__device__ __forceinline__ ushort f2bf(float f) {
    unsigned u = __builtin_bit_cast(unsigned, f);
    unsigned r = u + 0x7FFFu + ((u >> 16) & 1u);
    return (ushort)(r >> 16);
}

// ---------------------------------------------------------------------------
__global__ __launch_bounds__(64) void mask_kernel(
    const float* __restrict__ gum, const float* __restrict__ par,
    float* __restrict__ chm, float* __restrict__ out_tail)
{
    int c = threadIdx.x;
    #pragma unroll
    for (int i = 0; i < 4; ++i) {
        int base = (c*4 + i)*2;
        float g0 = -logf(-logf(gum[base]));
        float g1 = -logf(-logf(gum[base+1]));
        float a0 = par[base] + g0, a1 = par[base+1] + g1;
        float mx = fmaxf(a0, a1);
        float e0 = expf(a0 - mx), e1 = expf(a1 - mx);
        float inv = 1.0f / (e0 + e1);
        float m0 = e0*inv, m1 = e1*inv;
        chm[base] = m0; chm[base+1] = m1;
        out_tail[base] = m0; out_tail[base+1] = m1;
    }
}

// ---------------------------------------------------------------------------
// Build bf16 A-images (gate-folded weights) + bf16 pw weights.
__global__ __launch_bounds__(256) void prep_kernel(
    const float* __restrict__ w0, const float* __restrict__ w1,
    const float* __restrict__ w2, const float* __restrict__ w3,
    const float* __restrict__ wc, const float* __restrict__ chm,
    ushort* __restrict__ AH, ushort* __restrict__ pwA)
{
    int idx = blockIdx.x*256 + threadIdx.x;   // < 274432
    if (idx < 36864) {
        int blk = idx >> 11;            // c*9+t, 0..17
        int r3  = idx & 2047;
        int oc = r3 >> 5, icl = r3 & 31;
        int cc = blk / 9, t = blk - 9*cc;
        int ic = cc*32 + icl;
        AH[idx] = f2bf(w0[(oc*64 + ic)*9 + t]);
    } else if (idx < 258048) {
        int j = idx - 36864;
        int s = 1 + j / 73728;
        int r = j % 73728;
        int blk = r >> 12;              // 0..17
        int r3  = r & 4095;
        int ocM = r3 >> 5, icl = r3 & 31;
        int cc = blk / 9, t = blk - 9*cc;
        int ic = cc*32 + icl;
        int oc = ocM >> 1, set = ocM & 1;
        const float* wsrc = (s == 1) ? w1 : (s == 2 ? w2 : w3);
        AH[idx] = f2bf(wsrc[(oc*64 + ic)*9 + t] * chm[(ic*4 + s)*2 + set]);
    } else {
        int r = idx - 258048;           // < 16384
        pwA[r] = f2bf(wc[r]);
    }
}

// ---------------------------------------------------------------------------
// MFMA conv, pure bf16. Block = ROWS output rows of one b. M = 64*NSETS.
// Round-8: ROWS=2 amortization for the NSETS=2 stages. Per output row:
// staging rows 3->2 (4 input rows / 2 outputs), A-frag loads halved (each
// af feeds both rows' MFMAs), scatter LDS-writes x0.67. conv0 (INF32) keeps
// the r7-verified ROWS=1 path exactly (f32 staging regs too fat for ROWS=2).
// Single-phase schedule (r7-verified): both ic-chunks in LDS, ONE barrier.
// LDS per chunk sub-tile: (ROWS+2) rows x 130 cols x 36 ic-stride,
// sB[colIdx*36 + (ic ^ (((colIdx>>3)&7)<<2))] 3-bit XOR swizzle; reads =
// two aligned b64 loads reassembled in jj order. Halo zero: ONLY cols
// {rr*130+0, rr*130+129} (scatter writes cols 1..128; OOB rows scatter
// explicit zeros from zeroed staging regs). A-frag ring-4, 3-tap-ahead.
// acc declared/zeroed AFTER staging so its 128-AGPR (ROWS=2) lifetime does
// not overlap the 64-reg staging burst: peak ~212 of the 256-reg budget.
// Dynamic LDS (74,880 B @ROWS=2 exceeds the 64KB static limit); 2 blocks/CU.
template<int NSETS, bool INF32, int ROWS>
__global__ __launch_bounds__(256, 2) void conv_bf16(
    const void* __restrict__ inv, const ushort* __restrict__ A,
    const float* __restrict__ chm, const float* __restrict__ spa,
    ushort* __restrict__ feaOut, int stage)
{
    constexpr int MOC  = 64*NSETS;
    constexpr int MT   = MOC/32;        // m-tiles per wave
    constexpr int RP2  = ROWS + 2;      // staged input rows
    constexpr int SUBT = RP2*130*36;    // u16 per chunk sub-tile
    constexpr int ITS  = RP2*2;         // v8s per chunk per thread
    constexpr int HB   = H_/ROWS;       // h-blocks per image
    constexpr int NBLK = B_*HB;         // grid size
    extern __shared__ ushort sB[];      // 2*SUBT u16

    const int tid  = threadIdx.x;
    const int lane = tid & 63, wave = tid >> 6;
    const int wrow = wave >> 1, wcol = wave & 1;
    const int q = lane >> 4, ln16 = lane & 15;
    // XCD-aware remap: contiguous (b,h) chunk per XCD. NBLK % 8 == 0.
    const int wk = (blockIdx.x & 7)*(NBLK/8) + (blockIdx.x >> 3);
    const int h0 = (wk % HB)*ROWS;      // HB is pow2 -> mask
    const int b  = wk / HB;

    int aRow[MT];
    #pragma unroll
    for (int m = 0; m < MT; ++m)
        aRow[m] = (wrow*(MOC/2) + m*16 + ln16)*32 + q*8;

    // staging registers (both chunks live until scatter) + A-frag ring
    v8s stg[2*ITS];
    v4f stgF[4*ITS];
    v8s af[4][MT];

    auto issue = [&](int c) {
        const int ic0 = c*32;
        #pragma unroll
        for (int it = 0; it < ITS; ++it) {
            int i  = it*256 + tid;     // [0, RP2*512)
            int ry = i >> 9;           // 0..RP2-1
            int r  = i & 511;
            int ic = r >> 4, wv = r & 15;
            int gh = h0 - 1 + ry;
            if constexpr (INF32) {
                v4f a0 = (v4f){0.f,0.f,0.f,0.f}, a1 = a0;
                if ((unsigned)gh < 128u) {
                    const float* s = (const float*)inv +
                        ((size_t)((b*C_ + ic0 + ic)*H_ + gh)*W_ + wv*8);
                    a0 = *(const v4f*)(const void*)s;
                    a1 = *(const v4f*)(const void*)(s + 4);
                }
                stgF[(c*ITS+it)*2] = a0; stgF[(c*ITS+it)*2+1] = a1;
            } else {
                v8s v = (v8s){0,0,0,0,0,0,0,0};
                if ((unsigned)gh < 128u)
                    v = *(const v8s*)(const void*)((const ushort*)inv +
                        ((size_t)((b*C_ + ic0 + ic)*H_ + gh)*W_ + wv*8));
                stg[c*ITS+it] = v;
            }
        }
    };
    auto scatter = [&](int c) {
        ushort* sBc = sB + c*SUBT;
        #pragma unroll
        for (int it = 0; it < ITS; ++it) {
            int i  = it*256 + tid;
            int ry = i >> 9;
            int r  = i & 511;
            int ic = r >> 4, wv = r & 15;
            int colBase = ry*130 + wv*8 + 1;
            ushort vals[8];
            if constexpr (INF32) {
                #pragma unroll
                for (int j = 0; j < 4; ++j) {
                    vals[j]   = f2bf(stgF[(c*ITS+it)*2][j]);
                    vals[4+j] = f2bf(stgF[(c*ITS+it)*2+1][j]);
                }
            } else {
                #pragma unroll
                for (int j = 0; j < 8; ++j) vals[j] = (ushort)stg[c*ITS+it][j];
            }
            #pragma unroll
            for (int j = 0; j < 8; ++j) {
                int colIdx = colBase + j;
                int s3 = (colIdx >> 3) & 7;
                sBc[colIdx*36 + (ic ^ (s3 << 2))] = vals[j];
            }
        }
    };
    auto prolog = [&]() {
        #pragma unroll
        for (int tp = 0; tp < 3; ++tp)
            #pragma unroll
            for (int m = 0; m < MT; ++m)
                af[tp][m] = *(const v8s*)(const void*)(A + tp*MOC*32 + aRow[m]);
    };

    // -------- single-phase schedule (r7-verified) --------
    issue(0);                 // chunk-0 fea loads in flight
    issue(1);                 // chunk-1 fea loads in flight
    prolog();                 // A taps 0-2 in flight
    // zero ONLY halo columns of both sub-tiles (disjoint from scatter).
    for (int e = tid; e < RP2*72; e += 256) {
        int colSel = e / 36;            // 0..RP2*2-1
        int icz    = e - colSel*36;     // 0..35
        int rr     = colSel >> 1;
        int colIdx = rr*130 + ((colSel & 1) ? 129 : 0);
        sB[colIdx*36 + icz] = 0;
        sB[SUBT + colIdx*36 + icz] = 0;
    }
    scatter(0);               // waits chunk-0 loads; chunk-1 stays in flight
    scatter(1);
    __syncthreads();          // the ONLY barrier: both tiles + halos ready

    // acc declared here (after staging) so the 128-AGPR lifetime (ROWS=2)
    // does not overlap the staging registers.
    v4f acc[MT][ROWS][4];
    #pragma unroll
    for (int m = 0; m < MT; ++m)
        #pragma unroll
        for (int r = 0; r < ROWS; ++r)
            #pragma unroll
            for (int n = 0; n < 4; ++n) acc[m][r][n] = (v4f){0.f,0.f,0.f,0.f};

    // 18 uninterrupted tap-steps; each af feeds ROWS rows' MFMAs.
    #pragma unroll
    for (int tt = 0; tt < 18; ++tt) {
        if (tt < 15) {
            #pragma unroll
            for (int m = 0; m < MT; ++m)
                af[(tt+3)&3][m] = *(const v8s*)(const void*)(A + (tt+3)*MOC*32 + aRow[m]);
        }
        const int c  = tt/9, t = tt - 9*c;
        const int ky = t/3, kx = t - 3*(t/3);
        const ushort* sBc = sB + c*SUBT;
        #pragma unroll
        for (int nt = 0; nt < 4; ++nt) {
            #pragma unroll
            for (int r = 0; r < ROWS; ++r) {
                int colIdx = (ky + r)*130 + wcol*64 + nt*16 + ln16 + kx;
                int s3 = (colIdx >> 3) & 7;
                int base = colIdx*36 + ((q ^ (s3 >> 1)) << 3);
                int lo = base + ((s3 & 1) << 2);
                int hi = base + (((s3 & 1) ^ 1) << 2);
                v4s va = *(const v4s*)(const void*)(sBc + lo);   // ic jj 0..3
                v4s vb = *(const v4s*)(const void*)(sBc + hi);   // ic jj 4..7
                v8s bf = __builtin_shufflevector(va, vb, 0, 1, 2, 3, 4, 5, 6, 7);
                #pragma unroll
                for (int m = 0; m < MT; ++m)
                    acc[m][r][nt] = __builtin_amdgcn_mfma_f32_16x16x32_bf16(af[tt&3][m], bf, acc[m][r][nt], 0, 0, 0);
            }
        }
    }

    // epilogue: gates + relu, bf16 store (r4/r7-verified algebra, per row)
    #pragma unroll
    for (int r = 0; r < ROWS; ++r) {
        const int h = h0 + r;
        const float* spaRow = &spa[b*HW_ + h*W_];
        #pragma unroll
        for (int nt = 0; nt < 4; ++nt) {
            int px = wcol*64 + nt*16 + ln16;
            float sp = spaRow[px];
            #pragma unroll
            for (int m = 0; m < MT; ++m) {
                if constexpr (NSETS == 2) {
                    #pragma unroll
                    for (int rp = 0; rp < 2; ++rp) {
                        int oc = wrow*32 + m*8 + q*2 + rp;
                        float md = chm[(oc*4 + stage)*2 + 0];
                        float ms = chm[(oc*4 + stage)*2 + 1];
                        float f = acc[m][r][nt][2*rp]*(ms*sp + md)
                                + acc[m][r][nt][2*rp+1]*((ms + md)*sp);
                        feaOut[((size_t)(b*C_ + oc)*H_ + h)*W_ + px] = f2bf(fmaxf(f, 0.f));
                    }
                } else {
                    #pragma unroll
                    for (int rr4 = 0; rr4 < 4; ++rr4) {
                        int oc = wrow*32 + m*16 + q*4 + rr4;
                        float md = chm[(oc*4 + stage)*2 + 0];
                        float ms = chm[(oc*4 + stage)*2 + 1];
                        float f = acc[m][r][nt][rr4]*(ms*sp + md);
                        feaOut[((size_t)(b*C_ + oc)*H_ + h)*W_ + px] = f2bf(fmaxf(f, 0.f));
                    }
                }
            }
        }
    }
}

// ---------------------------------------------------------------------------
// Final pointwise: out[b,o,px] = sum_{k=0..255} wc[o][k]*fea_{k/64}[k%64][px] + bc[o]
// Block = 64 px of one (b,h) row. MFMA: M=64, N=64, K=256.
// (exact r4/r7 verified version)
__global__ __launch_bounds__(256, 2) void pw_final(
    const ushort* __restrict__ fea, const ushort* __restrict__ pwA,
    const float* __restrict__ bc, float* __restrict__ out)
{
    __shared__ __align__(16) ushort sF[64*260];   // 33280 B

    const int tid  = threadIdx.x;
    const int lane = tid & 63, wave = tid >> 6;
    const int wrow = wave >> 1, wcol = wave & 1;
    const int q = lane >> 4, ln16 = lane & 15;
    const int half = blockIdx.x & 1;
    const int h = (blockIdx.x >> 1) & 127;
    const int b = blockIdx.x >> 8;
    const int px0 = half*64;

    {
        v8s stg[8];
        #pragma unroll
        for (int it = 0; it < 8; ++it) {
            int i  = it*256 + tid;   // [0,2048)
            int s  = i >> 9;
            int r  = i & 511;
            int ic = r >> 3, pxv = r & 7;
            stg[it] = *(const v8s*)(const void*)(
                fea + (size_t)s*OUT_ELEMS + ((size_t)(b*C_ + ic)*H_ + h)*W_ + px0 + pxv*8);
        }
        #pragma unroll
        for (int it = 0; it < 8; ++it) {
            int i  = it*256 + tid;
            int s  = i >> 9;
            int r  = i & 511;
            int ic = r >> 3, pxv = r & 7;
            int kS = (s*64 + ic) ^ ((pxv & 3) << 3);
            ushort* dst = &sF[(pxv*8)*260 + kS];
            #pragma unroll
            for (int j = 0; j < 8; ++j) dst[j*260] = (ushort)stg[it][j];
        }
    }
    __syncthreads();

    v4f acc[2][2];
    #pragma unroll
    for (int m = 0; m < 2; ++m)
        #pragma unroll
        for (int n = 0; n < 2; ++n) acc[m][n] = (v4f){0.f, 0.f, 0.f, 0.f};

    #pragma unroll
    for (int ks = 0; ks < 8; ++ks) {
        v8s a[2];
        #pragma unroll
        for (int m = 0; m < 2; ++m)
            a[m] = *(const v8s*)(const void*)(pwA + (wrow*32 + m*16 + ln16)*256 + ks*32 + q*8);
        #pragma unroll
        for (int n = 0; n < 2; ++n) {
            int px = wcol*32 + n*16 + ln16;
            int swz = (px >> 3) & 3;
            v4s va = *(const v4s*)(const void*)(sF + px*260 + ks*32 + ((q ^ swz) << 3));
            v4s vb = *(const v4s*)(const void*)(sF + px*260 + ks*32 + ((q ^ swz) << 3) + 4);
            v8s bf = __builtin_shufflevector(va, vb, 0, 1, 2, 3, 4, 5, 6, 7);
            #pragma unroll
            for (int m = 0; m < 2; ++m)
                acc[m][n] = __builtin_amdgcn_mfma_f32_16x16x32_bf16(a[m], bf, acc[m][n], 0, 0, 0);
        }
    }

    #pragma unroll
    for (int n = 0; n < 2; ++n) {
        int px = px0 + wcol*32 + n*16 + ln16;
        #pragma unroll
        for (int m = 0; m < 2; ++m)
            #pragma unroll
            for (int r = 0; r < 4; ++r) {
                int o = wrow*32 + m*16 + q*4 + r;
                out[((size_t)(b*C_ + o)*H_ + h)*W_ + px] = acc[m][n][r] + bc[o];
            }
    }
}

// ---------------------------------------------------------------------------
extern "C" void kernel_launch(void* const* d_in, const int* in_sizes, int n_in,
                              void* d_out, int out_size, void* d_ws, size_t ws_size,
                              hipStream_t stream)
{
    const float* x0  = (const float*)d_in[0];
    const float* spa = (const float*)d_in[1];
    const float* gum = (const float*)d_in[2];
    const float* par = (const float*)d_in[3];
    const float* w0  = (const float*)d_in[4];
    const float* w1  = (const float*)d_in[5];
    const float* w2  = (const float*)d_in[6];
    const float* w3  = (const float*)d_in[7];
    const float* wc  = (const float*)d_in[8];
    const float* bc  = (const float*)d_in[9];
    float* out = (float*)d_out;
    char*  ws  = (char*)d_ws;

    float*  chm = (float*)(ws + CHM_B);
    ushort* pwA = (ushort*)(ws + PWA_B);
    ushort* AH  = (ushort*)(ws + AH_B);
    ushort* fea0 = (ushort*)(ws + FEA_B(0));
    ushort* fea1 = (ushort*)(ws + FEA_B(1));
    ushort* fea2 = (ushort*)(ws + FEA_B(2));
    ushort* fea3 = (ushort*)(ws + FEA_B(3));

    // dynamic LDS: 2 chunks x (ROWS+2)*130*36 u16
    const size_t lds1 = 2u*(1+2)*130*36*2;   // 56160 B (ROWS=1)
    const size_t lds2 = 2u*(2+2)*130*36*2;   // 74880 B (ROWS=2)

    mask_kernel<<<1, 64, 0, stream>>>(gum, par, chm, out + OUT_ELEMS);
    prep_kernel<<<1072, 256, 0, stream>>>(w0, w1, w2, w3, wc, chm, AH, pwA);

    conv_bf16<1, true , 1><<<2048, 256, lds1, stream>>>(x0,   AH + A_S0,  chm, spa, fea0, 0);
    conv_bf16<2, false, 2><<<1024, 256, lds2, stream>>>(fea0, AH + A_S(1), chm, spa, fea1, 1);
    conv_bf16<2, false, 2><<<1024, 256, lds2, stream>>>(fea1, AH + A_S(2), chm, spa, fea2, 2);
    conv_bf16<2, false, 2><<<1024, 256, lds2, stream>>>(fea2, AH + A_S(3), chm, spa, fea3, 3);

    pw_final<<<4096, 256, 0, stream>>>(fea0, pwA, bc, out);
}

// Round 9
// 378.513 us; speedup vs baseline: 1.2270x; 1.2270x over previous
//
#include <hip/hip_runtime.h>
#include <math.h>

// Problem constants
#define B_ 16
#define C_ 64
#define H_ 128
#define W_ 128
#define HW_ (H_*W_)
#define OUT_ELEMS 16777216   // B*C*H*W

// Workspace byte offsets
#define CHM_B    0                      // 512 f32
#define PWA_B    2048                   // 16384 u16
#define AH_B     34816                  // 258048 u16
#define FEA_B(s) (550912u + (size_t)(s)*33554432u)  // 4 x 16777216 u16

// A-image u16 offsets within AH
#define A_S0   0
#define A_S(s) (36864 + ((s)-1)*73728)  // s = 1..3

// LDS sub-tile size (u16 elems): 3 rows x 130 cols x 36 stride
#define SUBT 14040

typedef __attribute__((ext_vector_type(4))) short  v4s;
typedef __attribute__((ext_vector_type(8))) short  v8s;
typedef __attribute__((ext_vector_type(4))) float  v4f;

__device__ __forceinline__ ushort f2bf(float f) {
    unsigned u = __builtin_bit_cast(unsigned, f);
    unsigned r = u + 0x7FFFu + ((u >> 16) & 1u);
    return (ushort)(r >> 16);
}

// ---------------------------------------------------------------------------
__global__ __launch_bounds__(64) void mask_kernel(
    const float* __restrict__ gum, const float* __restrict__ par,
    float* __restrict__ chm, float* __restrict__ out_tail)
{
    int c = threadIdx.x;
    #pragma unroll
    for (int i = 0; i < 4; ++i) {
        int base = (c*4 + i)*2;
        float g0 = -logf(-logf(gum[base]));
        float g1 = -logf(-logf(gum[base+1]));
        float a0 = par[base] + g0, a1 = par[base+1] + g1;
        float mx = fmaxf(a0, a1);
        float e0 = expf(a0 - mx), e1 = expf(a1 - mx);
        float inv = 1.0f / (e0 + e1);
        float m0 = e0*inv, m1 = e1*inv;
        chm[base] = m0; chm[base+1] = m1;
        out_tail[base] = m0; out_tail[base+1] = m1;
    }
}

// ---------------------------------------------------------------------------
// Build bf16 A-images (gate-folded weights) + bf16 pw weights.
__global__ __launch_bounds__(256) void prep_kernel(
    const float* __restrict__ w0, const float* __restrict__ w1,
    const float* __restrict__ w2, const float* __restrict__ w3,
    const float* __restrict__ wc, const float* __restrict__ chm,
    ushort* __restrict__ AH, ushort* __restrict__ pwA)
{
    int idx = blockIdx.x*256 + threadIdx.x;   // < 274432
    if (idx < 36864) {
        int blk = idx >> 11;            // c*9+t, 0..17
        int r3  = idx & 2047;
        int oc = r3 >> 5, icl = r3 & 31;
        int cc = blk / 9, t = blk - 9*cc;
        int ic = cc*32 + icl;
        AH[idx] = f2bf(w0[(oc*64 + ic)*9 + t]);
    } else if (idx < 258048) {
        int j = idx - 36864;
        int s = 1 + j / 73728;
        int r = j % 73728;
        int blk = r >> 12;              // 0..17
        int r3  = r & 4095;
        int ocM = r3 >> 5, icl = r3 & 31;
        int cc = blk / 9, t = blk - 9*cc;
        int ic = cc*32 + icl;
        int oc = ocM >> 1, set = ocM & 1;
        const float* wsrc = (s == 1) ? w1 : (s == 2 ? w2 : w3);
        AH[idx] = f2bf(wsrc[(oc*64 + ic)*9 + t] * chm[(ic*4 + s)*2 + set]);
    } else {
        int r = idx - 258048;           // < 16384
        pwA[r] = f2bf(wc[r]);
    }
}

// ---------------------------------------------------------------------------
// MFMA conv, pure bf16. Block = one (b,h) row, 128 px. M = 64*NSETS rows.
// Round-9 = round-7 (verified 388.5us) + B-fragment register pipelining.
// r7 evidence: VGPR=104 of 256 budget; block wall 41.5K cy vs ~5K cy/wave
// issue -> dependent ds_read->MFMA chain is the stall; r5/r6/r8 proved both
// occupancy and ROWS=2 amortization spill. So: spend idle regs on a ring-3
// B-frag buffer (48 VGPR) loading tap tt+2's ds_reads before tap tt's MFMAs
// (2 taps x ~130cy issue cover >= ~120cy LDS latency).
// Single-phase schedule: both 32-ic chunks staged into 2 LDS sub-tiles,
// ONE barrier, 18 uninterrupted tap-steps.
// LDS per sub-tile: sB[colIdx*36 + (ic ^ (((colIdx>>3)&7)<<2))] — 3-bit XOR
// swizzle (4-way write conflict); reads = two aligned b64 loads reassembled
// in jj order. Halo zero: ONLY cols {ry*130+0, ry*130+129}, disjoint from
// scatter (cols 1..128; OOB rows scatter explicit zeros). A-frags: ring-4.
template<int NSETS, bool INF32>
__global__ __launch_bounds__(256, 2) void conv_bf16(
    const void* __restrict__ inv, const ushort* __restrict__ A,
    const float* __restrict__ chm, const float* __restrict__ spa,
    ushort* __restrict__ feaOut, int stage)
{
    constexpr int MOC = 64*NSETS;
    constexpr int MT  = MOC/32;     // m-tiles per wave
    __shared__ __align__(16) ushort sB[2*SUBT]; // 56160 B

    const int tid  = threadIdx.x;
    const int lane = tid & 63, wave = tid >> 6;
    const int wrow = wave >> 1, wcol = wave & 1;
    const int q = lane >> 4, ln16 = lane & 15;
    // XCD-aware remap (grid 2048 = 8*256): contiguous (b,h) chunk per XCD.
    const int wk = (blockIdx.x & 7)*256 + (blockIdx.x >> 3);
    const int h = wk & 127, b = wk >> 7;

    v4f acc[MT][4];
    #pragma unroll
    for (int m = 0; m < MT; ++m)
        #pragma unroll
        for (int n = 0; n < 4; ++n) acc[m][n] = (v4f){0.f, 0.f, 0.f, 0.f};

    int aRow[MT];
    #pragma unroll
    for (int m = 0; m < MT; ++m)
        aRow[m] = (wrow*(MOC/2) + m*16 + ln16)*32 + q*8;

    // staging registers (both chunks live until scatter) + A-frag ring
    v8s stg[12];
    v4f stgF[24];
    v8s af[4][MT];

    auto issue = [&](int c) {
        const int ic0 = c*32;
        #pragma unroll
        for (int it = 0; it < 6; ++it) {
            int i  = it*256 + tid;     // [0,1536)
            int ry = i >> 9;           // 0..2
            int r  = i & 511;
            int ic = r >> 4, wv = r & 15;
            int gh = h - 1 + ry;
            if constexpr (INF32) {
                v4f a0 = (v4f){0.f,0.f,0.f,0.f}, a1 = a0;
                if ((unsigned)gh < 128u) {
                    const float* s = (const float*)inv +
                        ((size_t)((b*C_ + ic0 + ic)*H_ + gh)*W_ + wv*8);
                    a0 = *(const v4f*)(const void*)s;
                    a1 = *(const v4f*)(const void*)(s + 4);
                }
                stgF[(c*6+it)*2] = a0; stgF[(c*6+it)*2+1] = a1;
            } else {
                v8s v = (v8s){0,0,0,0,0,0,0,0};
                if ((unsigned)gh < 128u)
                    v = *(const v8s*)(const void*)((const ushort*)inv +
                        ((size_t)((b*C_ + ic0 + ic)*H_ + gh)*W_ + wv*8));
                stg[c*6+it] = v;
            }
        }
    };
    auto scatter = [&](int c) {
        ushort* sBc = sB + c*SUBT;
        #pragma unroll
        for (int it = 0; it < 6; ++it) {
            int i  = it*256 + tid;
            int ry = i >> 9;
            int r  = i & 511;
            int ic = r >> 4, wv = r & 15;
            int colBase = ry*130 + wv*8 + 1;
            ushort vals[8];
            if constexpr (INF32) {
                #pragma unroll
                for (int j = 0; j < 4; ++j) {
                    vals[j]   = f2bf(stgF[(c*6+it)*2][j]);
                    vals[4+j] = f2bf(stgF[(c*6+it)*2+1][j]);
                }
            } else {
                #pragma unroll
                for (int j = 0; j < 8; ++j) vals[j] = (ushort)stg[c*6+it][j];
            }
            #pragma unroll
            for (int j = 0; j < 8; ++j) {
                int colIdx = colBase + j;
                int s3 = (colIdx >> 3) & 7;
                sBc[colIdx*36 + (ic ^ (s3 << 2))] = vals[j];
            }
        }
    };
    auto prolog = [&]() {
        #pragma unroll
        for (int tp = 0; tp < 3; ++tp)
            #pragma unroll
            for (int m = 0; m < MT; ++m)
                af[tp][m] = *(const v8s*)(const void*)(A + tp*MOC*32 + aRow[m]);
    };
    // B-fragment loader for tap-step tt (compile-time after unroll).
    auto loadB = [&](int tt, v8s* dst) {
        const int c  = tt/9, t = tt - 9*c;
        const int ky = t/3, kx = t - 3*(t/3);
        const ushort* sBc = sB + c*SUBT;
        #pragma unroll
        for (int nt = 0; nt < 4; ++nt) {
            int colIdx = ky*130 + wcol*64 + nt*16 + ln16 + kx;
            int s3 = (colIdx >> 3) & 7;
            int base = colIdx*36 + ((q ^ (s3 >> 1)) << 3);
            int lo = base + ((s3 & 1) << 2);
            int hi = base + (((s3 & 1) ^ 1) << 2);
            v4s va = *(const v4s*)(const void*)(sBc + lo);   // ic jj 0..3
            v4s vb = *(const v4s*)(const void*)(sBc + hi);   // ic jj 4..7
            dst[nt] = __builtin_shufflevector(va, vb, 0, 1, 2, 3, 4, 5, 6, 7);
        }
    };

    // -------- single-phase schedule (r7-verified) --------
    issue(0);                 // chunk-0 fea loads in flight
    issue(1);                 // chunk-1 fea loads in flight (12 total)
    prolog();                 // A taps 0-2 in flight
    // zero ONLY halo columns of both sub-tiles (disjoint from scatter).
    if (tid < 216) {
        int colSel = tid / 36;          // 0..5
        int icz    = tid - colSel*36;   // 0..35
        int ry     = colSel >> 1;
        int colIdx = ry*130 + ((colSel & 1) ? 129 : 0);
        sB[colIdx*36 + icz] = 0;
        sB[SUBT + colIdx*36 + icz] = 0;
    }
    scatter(0);               // waits chunk-0 loads; chunk-1 stays in flight
    scatter(1);
    __syncthreads();          // the ONLY barrier: both tiles + halos ready

    // 18 tap-steps, B-frags pipelined 2 ahead (ring-3), A-frags 3 ahead.
    v8s bf[3][4];
    loadB(0, bf[0]);
    loadB(1, bf[1]);
    #pragma unroll
    for (int tt = 0; tt < 18; ++tt) {
        if (tt < 16) loadB(tt+2, bf[(tt+2)%3]);
        if (tt < 15) {
            #pragma unroll
            for (int m = 0; m < MT; ++m)
                af[(tt+3)&3][m] = *(const v8s*)(const void*)(A + (tt+3)*MOC*32 + aRow[m]);
        }
        #pragma unroll
        for (int nt = 0; nt < 4; ++nt)
            #pragma unroll
            for (int m = 0; m < MT; ++m)
                acc[m][nt] = __builtin_amdgcn_mfma_f32_16x16x32_bf16(af[tt&3][m], bf[tt%3][nt], acc[m][nt], 0, 0, 0);
    }

    // epilogue: gates + relu, bf16 store (round-4/7 verified algebra)
    const float* spaRow = &spa[b*HW_ + h*W_];
    #pragma unroll
    for (int nt = 0; nt < 4; ++nt) {
        int px = wcol*64 + nt*16 + ln16;
        float sp = spaRow[px];
        #pragma unroll
        for (int m = 0; m < MT; ++m) {
            if constexpr (NSETS == 2) {
                #pragma unroll
                for (int rp = 0; rp < 2; ++rp) {
                    int oc = wrow*32 + m*8 + q*2 + rp;
                    float md = chm[(oc*4 + stage)*2 + 0];
                    float ms = chm[(oc*4 + stage)*2 + 1];
                    float f = acc[m][nt][2*rp]*(ms*sp + md)
                            + acc[m][nt][2*rp+1]*((ms + md)*sp);
                    feaOut[((size_t)(b*C_ + oc)*H_ + h)*W_ + px] = f2bf(fmaxf(f, 0.f));
                }
            } else {
                #pragma unroll
                for (int r = 0; r < 4; ++r) {
                    int oc = wrow*32 + m*16 + q*4 + r;
                    float md = chm[(oc*4 + stage)*2 + 0];
                    float ms = chm[(oc*4 + stage)*2 + 1];
                    float f = acc[m][nt][r]*(ms*sp + md);
                    feaOut[((size_t)(b*C_ + oc)*H_ + h)*W_ + px] = f2bf(fmaxf(f, 0.f));
                }
            }
        }
    }
}

// ---------------------------------------------------------------------------
// Final pointwise: out[b,o,px] = sum_{k=0..255} wc[o][k]*fea_{k/64}[k%64][px] + bc[o]
// Block = 64 px of one (b,h) row. MFMA: M=64, N=64, K=256.
// (exact r4/r7 verified version)
__global__ __launch_bounds__(256, 2) void pw_final(
    const ushort* __restrict__ fea, const ushort* __restrict__ pwA,
    const float* __restrict__ bc, float* __restrict__ out)
{
    __shared__ __align__(16) ushort sF[64*260];   // 33280 B

    const int tid  = threadIdx.x;
    const int lane = tid & 63, wave = tid >> 6;
    const int wrow = wave >> 1, wcol = wave & 1;
    const int q = lane >> 4, ln16 = lane & 15;
    const int half = blockIdx.x & 1;
    const int h = (blockIdx.x >> 1) & 127;
    const int b = blockIdx.x >> 8;
    const int px0 = half*64;

    {
        v8s stg[8];
        #pragma unroll
        for (int it = 0; it < 8; ++it) {
            int i  = it*256 + tid;   // [0,2048)
            int s  = i >> 9;
            int r  = i & 511;
            int ic = r >> 3, pxv = r & 7;
            stg[it] = *(const v8s*)(const void*)(
                fea + (size_t)s*OUT_ELEMS + ((size_t)(b*C_ + ic)*H_ + h)*W_ + px0 + pxv*8);
        }
        #pragma unroll
        for (int it = 0; it < 8; ++it) {
            int i  = it*256 + tid;
            int s  = i >> 9;
            int r  = i & 511;
            int ic = r >> 3, pxv = r & 7;
            int kS = (s*64 + ic) ^ ((pxv & 3) << 3);
            ushort* dst = &sF[(pxv*8)*260 + kS];
            #pragma unroll
            for (int j = 0; j < 8; ++j) dst[j*260] = (ushort)stg[it][j];
        }
    }
    __syncthreads();

    v4f acc[2][2];
    #pragma unroll
    for (int m = 0; m < 2; ++m)
        #pragma unroll
        for (int n = 0; n < 2; ++n) acc[m][n] = (v4f){0.f, 0.f, 0.f, 0.f};

    #pragma unroll
    for (int ks = 0; ks < 8; ++ks) {
        v8s a[2];
        #pragma unroll
        for (int m = 0; m < 2; ++m)
            a[m] = *(const v8s*)(const void*)(pwA + (wrow*32 + m*16 + ln16)*256 + ks*32 + q*8);
        #pragma unroll
        for (int n = 0; n < 2; ++n) {
            int px = wcol*32 + n*16 + ln16;
            int swz = (px >> 3) & 3;
            v4s va = *(const v4s*)(const void*)(sF + px*260 + ks*32 + ((q ^ swz) << 3));
            v4s vb = *(const v4s*)(const void*)(sF + px*260 + ks*32 + ((q ^ swz) << 3) + 4);
            v8s bf = __builtin_shufflevector(va, vb, 0, 1, 2, 3, 4, 5, 6, 7);
            #pragma unroll
            for (int m = 0; m < 2; ++m)
                acc[m][n] = __builtin_amdgcn_mfma_f32_16x16x32_bf16(a[m], bf, acc[m][n], 0, 0, 0);
        }
    }

    #pragma unroll
    for (int n = 0; n < 2; ++n) {
        int px = px0 + wcol*32 + n*16 + ln16;
        #pragma unroll
        for (int m = 0; m < 2; ++m)
            #pragma unroll
            for (int r = 0; r < 4; ++r) {
                int o = wrow*32 + m*16 + q*4 + r;
                out[((size_t)(b*C_ + o)*H_ + h)*W_ + px] = acc[m][n][r] + bc[o];
            }
    }
}

// ---------------------------------------------------------------------------
extern "C" void kernel_launch(void* const* d_in, const int* in_sizes, int n_in,
                              void* d_out, int out_size, void* d_ws, size_t ws_size,
                              hipStream_t stream)
{
    const float* x0  = (const float*)d_in[0];
    const float* spa = (const float*)d_in[1];
    const float* gum = (const float*)d_in[2];
    const float* par = (const float*)d_in[3];
    const float* w0  = (const float*)d_in[4];
    const float* w1  = (const float*)d_in[5];
    const float* w2  = (const float*)d_in[6];
    const float* w3  = (const float*)d_in[7];
    const float* wc  = (const float*)d_in[8];
    const float* bc  = (const float*)d_in[9];
    float* out = (float*)d_out;
    char*  ws  = (char*)d_ws;

    float*  chm = (float*)(ws + CHM_B);
    ushort* pwA = (ushort*)(ws + PWA_B);
    ushort* AH  = (ushort*)(ws + AH_B);
    ushort* fea0 = (ushort*)(ws + FEA_B(0));
    ushort* fea1 = (ushort*)(ws + FEA_B(1));
    ushort* fea2 = (ushort*)(ws + FEA_B(2));
    ushort* fea3 = (ushort*)(ws + FEA_B(3));

    mask_kernel<<<1, 64, 0, stream>>>(gum, par, chm, out + OUT_ELEMS);
    prep_kernel<<<1072, 256, 0, stream>>>(w0, w1, w2, w3, wc, chm, AH, pwA);

    conv_bf16<1, true ><<<2048, 256, 0, stream>>>(x0,   AH + A_S0,  chm, spa, fea0, 0);
    conv_bf16<2, false><<<2048, 256, 0, stream>>>(fea0, AH + A_S(1), chm, spa, fea1, 1);
    conv_bf16<2, false><<<2048, 256, 0, stream>>>(fea1, AH + A_S(2), chm, spa, fea2, 2);
    conv_bf16<2, false><<<2048, 256, 0, stream>>>(fea2, AH + A_S(3), chm, spa, fea3, 3);

    pw_final<<<4096, 256, 0, stream>>>(fea0, pwA, bc, out);
}